// Round 1
// baseline (65905.505 us; speedup 1.0000x reference)
//
#include <hip/hip_runtime.h>
#include <math.h>

#define HID 256
#define NGATE 1024   // 4*HID
#define TLEN 512
#define B_BLK 16

__device__ __forceinline__ float sigmoidf_(float x) {
    return 1.0f / (1.0f + __expf(-x));
}

__global__ __launch_bounds__(256, 2) void lstm_persistent_f32(
    const float* __restrict__ x,      // (B,1,1) flat B
    const float* __restrict__ W_ih,   // (1024,1) flat 1024
    const float* __restrict__ W_hh,   // (1024,256) row-major
    const float* __restrict__ b_ih,   // (1024,)
    const float* __restrict__ b_hh,   // (1024,)
    const float* __restrict__ W_fc,   // (1,256) flat 256
    const float* __restrict__ b_fc,   // (1,)
    float* __restrict__ out)          // (B, 512) flat
{
    const int tid = threadIdx.x;           // 0..255
    const int bbase = blockIdx.x * B_BLK;  // batch base for this block

    __shared__ float h_s[B_BLK][HID];   // 16 KiB
    __shared__ float wfc_s[HID];        // 1 KiB
    __shared__ float inp_s[B_BLK];

    // ---- init ----
    #pragma unroll
    for (int b = 0; b < B_BLK; ++b) h_s[b][tid] = 0.0f;
    wfc_s[tid] = W_fc[tid];
    if (tid < B_BLK) inp_s[tid] = x[bbase + tid];

    float c_r[B_BLK];
    #pragma unroll
    for (int b = 0; b < B_BLK; ++b) c_r[b] = 0.0f;

    // per-thread constants: thread owns gate rows g = tid + q*HID (q = i,f,g,o)
    float wih[4], bias[4];
    #pragma unroll
    for (int q = 0; q < 4; ++q) {
        int g = tid + q * HID;
        wih[q]  = W_ih[g];
        bias[q] = b_ih[g] + b_hh[g];
    }
    const float bfc = b_fc[0];

    __syncthreads();

    for (int t = 0; t < TLEN; ++t) {
        // ---- gates = bias + inp*W_ih + h @ W_hh^T ----
        float acc[B_BLK][4];
        #pragma unroll
        for (int b = 0; b < B_BLK; ++b) {
            float inp = inp_s[b];
            #pragma unroll
            for (int q = 0; q < 4; ++q)
                acc[b][q] = fmaf(inp, wih[q], bias[q]);
        }

        for (int k = 0; k < HID; k += 4) {
            float4 w[4];
            #pragma unroll
            for (int q = 0; q < 4; ++q)
                w[q] = *(const float4*)(W_hh + (size_t)(tid + q * HID) * HID + k);
            #pragma unroll
            for (int b = 0; b < B_BLK; ++b) {
                float4 hv = *(const float4*)(&h_s[b][k]);   // wave-uniform → LDS broadcast
                #pragma unroll
                for (int q = 0; q < 4; ++q) {
                    acc[b][q] = fmaf(hv.x, w[q].x, acc[b][q]);
                    acc[b][q] = fmaf(hv.y, w[q].y, acc[b][q]);
                    acc[b][q] = fmaf(hv.z, w[q].z, acc[b][q]);
                    acc[b][q] = fmaf(hv.w, w[q].w, acc[b][q]);
                }
            }
        }
        __syncthreads();   // all matvec reads of h_s complete

        // ---- elementwise LSTM cell update (thread tid owns hidden unit tid) ----
        #pragma unroll
        for (int b = 0; b < B_BLK; ++b) {
            float iv = sigmoidf_(acc[b][0]);
            float fv = sigmoidf_(acc[b][1]);
            float gv = tanhf(acc[b][2]);
            float ov = sigmoidf_(acc[b][3]);
            float c  = fmaf(fv, c_r[b], iv * gv);
            c_r[b]   = c;
            float h  = ov * tanhf(c);
            h_s[b][tid] = h;
        }
        __syncthreads();   // new h visible

        // ---- d = h @ W_fc^T + b_fc ; feed back as next input ----
        if (tid < B_BLK) {
            const int b = tid;
            float s = 0.0f;
            for (int j = 0; j < HID; ++j)
                s = fmaf(h_s[b][j], wfc_s[j], s);
            float d = s + bfc;
            out[(size_t)(bbase + b) * TLEN + t] = d;
            inp_s[b] = d;
        }
        __syncthreads();
    }
}

extern "C" void kernel_launch(void* const* d_in, const int* in_sizes, int n_in,
                              void* d_out, int out_size, void* d_ws, size_t ws_size,
                              hipStream_t stream) {
    const float* x    = (const float*)d_in[0];
    const float* W_ih = (const float*)d_in[1];
    const float* W_hh = (const float*)d_in[2];
    const float* b_ih = (const float*)d_in[3];
    const float* b_hh = (const float*)d_in[4];
    const float* W_fc = (const float*)d_in[5];
    const float* b_fc = (const float*)d_in[6];
    float* out = (float*)d_out;

    const int BATCH = in_sizes[0];          // 8192
    const int nblocks = BATCH / B_BLK;      // 512

    lstm_persistent_f32<<<nblocks, 256, 0, stream>>>(
        x, W_ih, W_hh, b_ih, b_hh, W_fc, b_fc, out);
}

// Round 2
// 39874.069 us; speedup vs baseline: 1.6528x; 1.6528x over previous
//
#include <hip/hip_runtime.h>
#include <math.h>

#define HID   256
#define NG    1024          // 4*HID
#define TLEN  512
#define BB    64            // batch per block
#define NWAVE 8             // 512 threads
#define NTHR  512

typedef __attribute__((ext_vector_type(8))) short short8;
typedef __attribute__((ext_vector_type(4))) float f32x4;

__device__ __forceinline__ unsigned short f2bf_rne(float x) {
    unsigned int u = __float_as_uint(x);
    unsigned int r = (u + 0x7FFFu + ((u >> 16) & 1u)) >> 16;
    return (unsigned short)r;
}
__device__ __forceinline__ float bf2f(unsigned short h) {
    return __uint_as_float(((unsigned int)h) << 16);
}
__device__ __forceinline__ float sigf(float x) {
    return 1.0f / (1.0f + __expf(-x));
}
__device__ __forceinline__ float tanhf_fast(float x) {
    return 1.0f - 2.0f / (1.0f + __expf(2.0f * x));
}

// ---- pack W_hh (f32 row-major [1024][256]) into MFMA B-fragment order ----
// tile t_idx = gt*8 + kc  (gt: 16-row gate tile, kc: 32-wide k chunk)
// layout: wp[t_idx*128 + sel*64 + lane] = short8 of W[{16gt+(l&15)}][{32kc+8(l>>4)} .. +7]
// sel 0 = hi bf16, sel 1 = lo bf16 (residual)
__global__ void pack_whh(const float* __restrict__ W, unsigned short* __restrict__ wp) {
    int idx  = blockIdx.x * 256 + threadIdx.x;   // 32768 total
    int lane = idx & 63;
    int t_idx = idx >> 6;                        // 0..511
    int gt = t_idx >> 3, kc = t_idx & 7;
    int g  = gt * 16 + (lane & 15);
    int k0 = kc * 32 + (lane >> 4) * 8;
    const float* src = W + (size_t)g * HID + k0;
    unsigned short* dhi = wp + ((size_t)t_idx * 128 + lane) * 8;
    unsigned short* dlo = wp + ((size_t)t_idx * 128 + 64 + lane) * 8;
    #pragma unroll
    for (int e = 0; e < 8; ++e) {
        float x = src[e];
        unsigned short hi = f2bf_rne(x);
        float res = x - bf2f(hi);
        dhi[e] = hi;
        dlo[e] = f2bf_rne(res);
    }
}

__global__ __launch_bounds__(NTHR, 2) void lstm_mfma(
    const float* __restrict__ x,      // (B,1,1)
    const float* __restrict__ W_ih,   // (1024,)
    const float* __restrict__ b_ih,   // (1024,)
    const float* __restrict__ b_hh,   // (1024,)
    const float* __restrict__ W_fc,   // (256,)
    const float* __restrict__ b_fc,   // (1,)
    const short8* __restrict__ wp,    // packed split-bf16 W_hh
    float* __restrict__ out)          // (B, 512)
{
    const int tid  = threadIdx.x;
    const int wave = tid >> 6;
    const int lane = tid & 63;
    const int l15  = lane & 15;
    const int l4   = lane >> 4;
    const int bbase = blockIdx.x * BB;

    __shared__ unsigned short hhi_s[BB][HID + 8];   // padded rows (+16B)
    __shared__ unsigned short hlo_s[BB][HID + 8];
    __shared__ float wfc_s[HID];
    __shared__ float inp_s[BB];

    // ---- init ----
    for (int i = tid; i < BB * (HID + 8); i += NTHR) {
        ((unsigned short*)hhi_s)[i] = 0;
        ((unsigned short*)hlo_s)[i] = 0;
    }
    for (int i = tid; i < HID; i += NTHR) wfc_s[i] = W_fc[i];
    if (tid < BB) inp_s[tid] = x[bbase + tid];

    // per-lane step-invariant constants: n = q*2+js -> gate row g
    float biasv[8], wihv[8];
    #pragma unroll
    for (int n = 0; n < 8; ++n) {
        int q = n >> 1, js = n & 1;
        int g = 256 * q + 32 * wave + 16 * js + l15;
        biasv[n] = b_ih[g] + b_hh[g];
        wihv[n]  = W_ih[g];
    }
    const float bfc = b_fc[0];

    float c_r[4][2][4];
    #pragma unroll
    for (int m = 0; m < 4; ++m)
        #pragma unroll
        for (int js = 0; js < 2; ++js)
            #pragma unroll
            for (int r = 0; r < 4; ++r) c_r[m][js][r] = 0.0f;

    __syncthreads();

    #pragma unroll 1
    for (int t = 0; t < TLEN; ++t) {
        // ---- acc init: bias + d*W_ih ----
        f32x4 acc[4][8];
        {
            float dv[4][4];
            #pragma unroll
            for (int m = 0; m < 4; ++m)
                #pragma unroll
                for (int r = 0; r < 4; ++r)
                    dv[m][r] = inp_s[16 * m + 4 * l4 + r];
            #pragma unroll
            for (int m = 0; m < 4; ++m)
                #pragma unroll
                for (int n = 0; n < 8; ++n)
                    #pragma unroll
                    for (int r = 0; r < 4; ++r)
                        acc[m][n][r] = fmaf(dv[m][r], wihv[n], biasv[n]);
        }

        // ---- MFMA phase: gates += h @ W_hh^T (4-term split bf16) ----
        #pragma unroll
        for (int kc = 0; kc < 8; ++kc) {
            short8 ahi[4], alo[4];
            const int koff = kc * 32 + l4 * 8;
            #pragma unroll
            for (int m = 0; m < 4; ++m) {
                int row = 16 * m + l15;
                ahi[m] = *(const short8*)&hhi_s[row][koff];
                alo[m] = *(const short8*)&hlo_s[row][koff];
            }
            #pragma unroll
            for (int n = 0; n < 8; ++n) {
                int q = n >> 1, js = n & 1;
                int gt = 16 * q + 2 * wave + js;
                size_t idx = (size_t)(gt * 8 + kc) * 128 + lane;
                short8 bhi = wp[idx];
                short8 blo = wp[idx + 64];
                #pragma unroll
                for (int m = 0; m < 4; ++m) {
                    acc[m][n] = __builtin_amdgcn_mfma_f32_16x16x32_bf16(ahi[m], bhi, acc[m][n], 0, 0, 0);
                    acc[m][n] = __builtin_amdgcn_mfma_f32_16x16x32_bf16(alo[m], bhi, acc[m][n], 0, 0, 0);
                    acc[m][n] = __builtin_amdgcn_mfma_f32_16x16x32_bf16(ahi[m], blo, acc[m][n], 0, 0, 0);
                    acc[m][n] = __builtin_amdgcn_mfma_f32_16x16x32_bf16(alo[m], blo, acc[m][n], 0, 0, 0);
                }
            }
        }
        __syncthreads();   // B1: all h_s reads (and inp_s reads) done

        // ---- cell update (register-only; i,f,g,o same lane) + h split write ----
        #pragma unroll
        for (int m = 0; m < 4; ++m)
            #pragma unroll
            for (int js = 0; js < 2; ++js)
                #pragma unroll
                for (int r = 0; r < 4; ++r) {
                    float gi = acc[m][0 + js][r];
                    float gf = acc[m][2 + js][r];
                    float gg = acc[m][4 + js][r];
                    float go = acc[m][6 + js][r];
                    float c  = c_r[m][js][r];
                    c = fmaf(sigf(gf), c, sigf(gi) * tanhf_fast(gg));
                    c_r[m][js][r] = c;
                    float h = sigf(go) * tanhf_fast(c);
                    int b = 16 * m + 4 * l4 + r;
                    int j = 32 * wave + 16 * js + l15;
                    unsigned short hh = f2bf_rne(h);
                    float hres = h - bf2f(hh);
                    hhi_s[b][j] = hh;
                    hlo_s[b][j] = f2bf_rne(hres);
                }
        __syncthreads();   // B2: new h visible

        // ---- d = h @ W_fc^T + b_fc ; feedback ----
        {
            int b = tid >> 3;       // 0..63
            int p = tid & 7;        // 8 threads per batch
            float s = 0.0f;
            #pragma unroll
            for (int i2 = 0; i2 < 8; ++i2) {
                int j = p * 32 + i2 * 4;
                ushort4 vh = *(const ushort4*)&hhi_s[b][j];
                ushort4 vl = *(const ushort4*)&hlo_s[b][j];
                s = fmaf(bf2f(vh.x) + bf2f(vl.x), wfc_s[j + 0], s);
                s = fmaf(bf2f(vh.y) + bf2f(vl.y), wfc_s[j + 1], s);
                s = fmaf(bf2f(vh.z) + bf2f(vl.z), wfc_s[j + 2], s);
                s = fmaf(bf2f(vh.w) + bf2f(vl.w), wfc_s[j + 3], s);
            }
            s += __shfl_xor(s, 1);
            s += __shfl_xor(s, 2);
            s += __shfl_xor(s, 4);
            if (p == 0) {
                float d = s + bfc;
                out[(size_t)(bbase + b) * TLEN + t] = d;
                inp_s[b] = d;
            }
        }
        __syncthreads();   // B3: d visible for next step's acc init
    }
}

extern "C" void kernel_launch(void* const* d_in, const int* in_sizes, int n_in,
                              void* d_out, int out_size, void* d_ws, size_t ws_size,
                              hipStream_t stream) {
    const float* x    = (const float*)d_in[0];
    const float* W_ih = (const float*)d_in[1];
    const float* W_hh = (const float*)d_in[2];
    const float* b_ih = (const float*)d_in[3];
    const float* b_hh = (const float*)d_in[4];
    const float* W_fc = (const float*)d_in[5];
    const float* b_fc = (const float*)d_in[6];
    float* out = (float*)d_out;

    const int BATCH   = in_sizes[0];        // 8192
    const int nblocks = BATCH / BB;         // 128

    // pack split-bf16 weights into workspace (1 MiB)
    pack_whh<<<128, 256, 0, stream>>>(W_hh, (unsigned short*)d_ws);
    lstm_mfma<<<nblocks, NTHR, 0, stream>>>(
        x, W_ih, b_ih, b_hh, W_fc, b_fc, (const short8*)d_ws, out);
}

// Round 3
// 25230.988 us; speedup vs baseline: 2.6121x; 1.5804x over previous
//
#include <hip/hip_runtime.h>
#include <math.h>

#define HID   256
#define NG    1024          // 4*HID
#define TLEN  512
#define BB    32            // batch per block
#define NTHR  512           // 8 waves

typedef __attribute__((ext_vector_type(8))) short short8;
typedef __attribute__((ext_vector_type(4))) float f32x4;

static __device__ __forceinline__ unsigned short f2bf_rne(float x) {
    unsigned int u = __float_as_uint(x);
    unsigned int r = (u + 0x7FFFu + ((u >> 16) & 1u)) >> 16;
    return (unsigned short)r;
}
static __device__ __forceinline__ float bf2f(unsigned short h) {
    return __uint_as_float(((unsigned int)h) << 16);
}
static __device__ __forceinline__ float sigf(float x) {
    return 1.0f / (1.0f + __expf(-x));
}
static __device__ __forceinline__ float tanhf_fast(float x) {
    return 1.0f - 2.0f / (1.0f + __expf(2.0f * x));
}

// ---- pack W_hh (f32 row-major [1024][256]) into MFMA B-fragment order ----
// tile t_idx = gt*8 + kc  (gt: 16-row gate tile, kc: 32-wide k chunk)
// wp[t_idx*128 + sel*64 + lane] = short8 of W[16gt+(l&15)][32kc+8(l>>4) .. +7]
// sel 0 = hi bf16, sel 1 = lo bf16 (residual)
__global__ void pack_whh(const float* __restrict__ W, unsigned short* __restrict__ wp) {
    int idx  = blockIdx.x * 256 + threadIdx.x;   // 32768 total
    int lane = idx & 63;
    int t_idx = idx >> 6;                        // 0..511
    int gt = t_idx >> 3, kc = t_idx & 7;
    int g  = gt * 16 + (lane & 15);
    int k0 = kc * 32 + (lane >> 4) * 8;
    const float* src = W + (size_t)g * HID + k0;
    unsigned short* dhi = wp + ((size_t)t_idx * 128 + lane) * 8;
    unsigned short* dlo = wp + ((size_t)t_idx * 128 + 64 + lane) * 8;
    #pragma unroll
    for (int e = 0; e < 8; ++e) {
        float x = src[e];
        unsigned short hi = f2bf_rne(x);
        float res = x - bf2f(hi);
        dhi[e] = hi;
        dlo[e] = f2bf_rne(res);
    }
}

__global__ __launch_bounds__(NTHR, 2) void lstm_mfma2(
    const float* __restrict__ x,      // (B,1,1)
    const float* __restrict__ W_ih,   // (1024,)
    const float* __restrict__ b_ih,   // (1024,)
    const float* __restrict__ b_hh,   // (1024,)
    const float* __restrict__ W_fc,   // (256,)
    const float* __restrict__ b_fc,   // (1,)
    const short8* __restrict__ wp,    // packed split-bf16 W_hh
    float* __restrict__ out)          // (B, 512)
{
    const int tid  = threadIdx.x;
    const int wave = tid >> 6;
    const int lane = tid & 63;
    const int l15  = lane & 15;
    const int l4   = lane >> 4;
    const int bbase = blockIdx.x * BB;

    // h planes stored in MFMA A-fragment order:
    // tile (m,kc) at [(m*8+kc)*512 .. +511]; element (row rw, k kw within 32-chunk)
    // lives at lane' = rw + 16*(kw>>3), elem = kw&7  -> addr = tile*512 + lane'*8 + elem
    __shared__ unsigned short hfhi[16 * 512];   // 16 KiB
    __shared__ unsigned short hflo[16 * 512];   // 16 KiB
    __shared__ float dpart[8][32];              // per-wave partial d sums
    __shared__ float inp_s[BB];

    for (int i = tid; i < 16 * 512; i += NTHR) { hfhi[i] = 0; hflo[i] = 0; }
    if (tid < BB) inp_s[tid] = x[bbase + tid];

    // per-lane step-invariant constants: n = 2q+js -> gate row g
    float biasv[8], wihv[8], wfc_r[2];
    #pragma unroll
    for (int n = 0; n < 8; ++n) {
        int q = n >> 1, js = n & 1;
        int g = 256 * q + 32 * wave + 16 * js + l15;
        biasv[n] = b_ih[g] + b_hh[g];
        wihv[n]  = W_ih[g];
    }
    wfc_r[0] = W_fc[32 * wave + l15];
    wfc_r[1] = W_fc[32 * wave + 16 + l15];
    const float bfc = b_fc[0];

    float c_r[2][2][4];
    #pragma unroll
    for (int m = 0; m < 2; ++m)
        #pragma unroll
        for (int js = 0; js < 2; ++js)
            #pragma unroll
            for (int r = 0; r < 4; ++r) c_r[m][js][r] = 0.0f;

    __syncthreads();

    #pragma unroll 1
    for (int t = 0; t < TLEN; ++t) {
        // ---- acc init: bias + d*W_ih ----
        f32x4 acc[2][8];
        {
            float dv[2][4];
            #pragma unroll
            for (int m = 0; m < 2; ++m)
                #pragma unroll
                for (int r = 0; r < 4; ++r)
                    dv[m][r] = inp_s[16 * m + 4 * l4 + r];
            #pragma unroll
            for (int m = 0; m < 2; ++m)
                #pragma unroll
                for (int n = 0; n < 8; ++n)
                    #pragma unroll
                    for (int r = 0; r < 4; ++r)
                        acc[m][n][r] = fmaf(dv[m][r], wihv[n], biasv[n]);
        }

        // ---- MFMA: gates += h @ W_hh^T (4-term split bf16) ----
        #pragma unroll
        for (int kc = 0; kc < 8; ++kc) {
            short8 ahi[2], alo[2];
            #pragma unroll
            for (int m = 0; m < 2; ++m) {
                int aoff = (m * 8 + kc) * 512 + lane * 8;
                ahi[m] = *(const short8*)&hfhi[aoff];   // linear: zero bank conflict
                alo[m] = *(const short8*)&hflo[aoff];
            }
            #pragma unroll
            for (int n = 0; n < 8; ++n) {
                int q = n >> 1, js = n & 1;
                int gt = 16 * q + 2 * wave + js;
                size_t idx = (size_t)(gt * 8 + kc) * 128 + lane;
                short8 bhi = wp[idx];
                short8 blo = wp[idx + 64];
                #pragma unroll
                for (int m = 0; m < 2; ++m) {
                    acc[m][n] = __builtin_amdgcn_mfma_f32_16x16x32_bf16(ahi[m], bhi, acc[m][n], 0, 0, 0);
                    acc[m][n] = __builtin_amdgcn_mfma_f32_16x16x32_bf16(alo[m], bhi, acc[m][n], 0, 0, 0);
                    acc[m][n] = __builtin_amdgcn_mfma_f32_16x16x32_bf16(ahi[m], blo, acc[m][n], 0, 0, 0);
                    acc[m][n] = __builtin_amdgcn_mfma_f32_16x16x32_bf16(alo[m], blo, acc[m][n], 0, 0, 0);
                }
            }
        }
        __syncthreads();   // B1: all h/inp reads done

        // ---- cell update (i,f,g,o same lane) + h write + d partials ----
        float ps[2][4];
        #pragma unroll
        for (int m = 0; m < 2; ++m)
            #pragma unroll
            for (int r = 0; r < 4; ++r) ps[m][r] = 0.0f;

        #pragma unroll
        for (int m = 0; m < 2; ++m)
            #pragma unroll
            for (int js = 0; js < 2; ++js)
                #pragma unroll
                for (int r = 0; r < 4; ++r) {
                    float gi = acc[m][0 + js][r];
                    float gf = acc[m][2 + js][r];
                    float gg = acc[m][4 + js][r];
                    float go = acc[m][6 + js][r];
                    float c  = c_r[m][js][r];
                    c = fmaf(sigf(gf), c, sigf(gi) * tanhf_fast(gg));
                    c_r[m][js][r] = c;
                    float h = sigf(go) * tanhf_fast(c);
                    unsigned short hh = f2bf_rne(h);
                    float hres = h - bf2f(hh);
                    // batch b = 16m+4*l4+r; hidden j = 32*wave+16*js+l15
                    int haddr = (m * 8 + wave) * 512
                              + ((4 * l4 + r) + 16 * (2 * js + (l15 >> 3))) * 8
                              + (l15 & 7);
                    hfhi[haddr] = hh;
                    hflo[haddr] = f2bf_rne(hres);
                    ps[m][r] = fmaf(h, wfc_r[js], ps[m][r]);
                }

        // reduce d partials over l15 (16 lanes share a batch row)
        #pragma unroll
        for (int m = 0; m < 2; ++m)
            #pragma unroll
            for (int r = 0; r < 4; ++r) {
                float s = ps[m][r];
                s += __shfl_xor(s, 1);
                s += __shfl_xor(s, 2);
                s += __shfl_xor(s, 4);
                s += __shfl_xor(s, 8);
                if (l15 == 0) dpart[wave][16 * m + 4 * l4 + r] = s;
            }
        __syncthreads();   // B2: h + dpart visible

        // ---- final d = sum over waves + b_fc ; feedback ----
        if (tid < BB) {
            int b = tid;
            float s = bfc;
            #pragma unroll
            for (int w = 0; w < 8; ++w) s += dpart[w][b];
            out[(size_t)(bbase + b) * TLEN + t] = s;
            inp_s[b] = s;
        }
        __syncthreads();   // B3: inp_s ready for next step
    }
}

extern "C" void kernel_launch(void* const* d_in, const int* in_sizes, int n_in,
                              void* d_out, int out_size, void* d_ws, size_t ws_size,
                              hipStream_t stream) {
    const float* x    = (const float*)d_in[0];
    const float* W_ih = (const float*)d_in[1];
    const float* W_hh = (const float*)d_in[2];
    const float* b_ih = (const float*)d_in[3];
    const float* b_hh = (const float*)d_in[4];
    const float* W_fc = (const float*)d_in[5];
    const float* b_fc = (const float*)d_in[6];
    float* out = (float*)d_out;

    const int BATCH   = in_sizes[0];        // 8192
    const int nblocks = BATCH / BB;         // 256 -> 1 block/CU

    pack_whh<<<128, 256, 0, stream>>>(W_hh, (unsigned short*)d_ws);
    lstm_mfma2<<<nblocks, NTHR, 0, stream>>>(
        x, W_ih, b_ih, b_hh, W_fc, b_fc, (const short8*)d_ws, out);
}